// Round 1
// baseline (1026.599 us; speedup 1.0000x reference)
//
#include <hip/hip_runtime.h>
#include <hip/hip_bf16.h>

typedef __hip_bfloat16 bf16;
typedef short bf16x8 __attribute__((ext_vector_type(8)));
typedef float f32x4 __attribute__((ext_vector_type(4)));

constexpr int C  = 192;
constexpr int HF = 128;
constexpr int HS = 64;
constexpr int L  = 4096;          // HS*HS

// ---------------- prep: downsample, bf16 split, parity images, ss ----------------
__global__ void prep_kernel(const float* __restrict__ f, const float* __restrict__ b,
                            bf16* __restrict__ fdh, bf16* __restrict__ fdl,
                            bf16* __restrict__ bdh, bf16* __restrict__ bdl,
                            bf16* __restrict__ bpar, float* __restrict__ ss, int batch){
    int pos = blockIdx.x;            // 0..4095  (p*64+q)
    int p = pos >> 6, q = pos & 63;
    int c = threadIdx.x;             // 0..191
    const float* fb = f + (size_t)batch * HF * HF * C;
    const float* bb = b + (size_t)batch * HF * HF * C;

    float fv = fb[((2*p)*HF + 2*q)*C + c];
    bf16 fh = __float2bfloat16(fv);
    fdh[(size_t)pos*C + c] = fh;
    fdl[(size_t)pos*C + c] = __float2bfloat16(fv - __bfloat162float(fh));

    float b00 = 0.f;
    #pragma unroll
    for (int dx = 0; dx < 2; dx++)
      #pragma unroll
      for (int dy = 0; dy < 2; dy++){
        float bv = bb[((2*p+dx)*HF + (2*q+dy))*C + c];
        int par = dx*2 + dy;
        // transposed patch index k' = q*64+p
        bpar[((size_t)par*L + (q*64+p))*C + c] = __float2bfloat16(bv);
        if (par == 0){
            b00 = bv;
            bf16 bh = __float2bfloat16(bv);
            bdh[(size_t)pos*C + c] = bh;
            bdl[(size_t)pos*C + c] = __float2bfloat16(bv - __bfloat162float(bh));
        }
      }

    // block-reduce sum of b00^2 over 192 threads (3 waves)
    __shared__ float red[3];
    float v = b00 * b00;
    #pragma unroll
    for (int o = 32; o > 0; o >>= 1) v += __shfl_down(v, o);
    if ((threadIdx.x & 63) == 0) red[threadIdx.x >> 6] = v;
    __syncthreads();
    if (threadIdx.x == 0) ss[pos] = red[0] + red[1] + red[2];
}

// ---------------- norm (3x3 window of ss) and mask mm (transposed layout) --------
__global__ void normmm_kernel(const float* __restrict__ mask, const float* __restrict__ ss,
                              float* __restrict__ rnorm, float* __restrict__ mmT){
    int pos = blockIdx.x*256 + threadIdx.x;  // p*64+q
    int p = pos >> 6, q = pos & 63;
    float s = 0.f, ms = 0.f;
    #pragma unroll
    for (int di = -1; di <= 1; di++)
      #pragma unroll
      for (int dj = -1; dj <= 1; dj++){
        int pp = p + di, qq = q + dj;
        if ((unsigned)pp < 64u && (unsigned)qq < 64u){
            s  += ss[pp*64 + qq];
            ms += mask[(2*pp)*HF + 2*qq];
        }
      }
    float n = fmaxf(sqrtf(s), 1e-4f);
    rnorm[pos] = 1.f / n;
    mmT[q*64 + p] = (ms == 0.f) ? 1.f : 0.f;
}

// ---------------- Gram GEMM: G[a,b] = sum_c fd[a,c]*bd[b,c], split-bf16 ----------
__global__ __launch_bounds__(256) void gemm_g(
        const bf16* __restrict__ fdh, const bf16* __restrict__ fdl,
        const bf16* __restrict__ bdh, const bf16* __restrict__ bdl,
        float* __restrict__ G){
    __shared__ __align__(16) bf16 Ah[128][40], Al[128][40], Bh[128][40], Bl[128][40];
    int t = threadIdx.x;
    int m0 = blockIdx.y * 128, n0 = blockIdx.x * 128;
    int wv = t >> 6, lane = t & 63, lr = lane & 15, lq = lane >> 4;
    int wm = (wv >> 1) * 64, wn = (wv & 1) * 64;
    f32x4 acc[4][4] = {};

    for (int kk = 0; kk < 6; kk++){
        int k0 = kk * 32;
        __syncthreads();
        #pragma unroll
        for (int r = 0; r < 2; r++){
            int e = r*256 + t; int row = e >> 2, kc = e & 3;
            *(uint4*)&Ah[row][kc*8] = *(const uint4*)(fdh + (size_t)(m0+row)*C + k0 + kc*8);
            *(uint4*)&Al[row][kc*8] = *(const uint4*)(fdl + (size_t)(m0+row)*C + k0 + kc*8);
            *(uint4*)&Bh[row][kc*8] = *(const uint4*)(bdh + (size_t)(n0+row)*C + k0 + kc*8);
            *(uint4*)&Bl[row][kc*8] = *(const uint4*)(bdl + (size_t)(n0+row)*C + k0 + kc*8);
        }
        __syncthreads();
        bf16x8 ah[4], al[4], bh[4], bl[4];
        #pragma unroll
        for (int mt = 0; mt < 4; mt++){
            ah[mt] = *(bf16x8*)&Ah[wm + mt*16 + lr][lq*8];
            al[mt] = *(bf16x8*)&Al[wm + mt*16 + lr][lq*8];
        }
        #pragma unroll
        for (int nt = 0; nt < 4; nt++){
            bh[nt] = *(bf16x8*)&Bh[wn + nt*16 + lr][lq*8];
            bl[nt] = *(bf16x8*)&Bl[wn + nt*16 + lr][lq*8];
        }
        #pragma unroll
        for (int mt = 0; mt < 4; mt++)
          #pragma unroll
          for (int nt = 0; nt < 4; nt++){
            acc[mt][nt] = __builtin_amdgcn_mfma_f32_16x16x32_bf16(ah[mt], bh[nt], acc[mt][nt], 0,0,0);
            acc[mt][nt] = __builtin_amdgcn_mfma_f32_16x16x32_bf16(ah[mt], bl[nt], acc[mt][nt], 0,0,0);
            acc[mt][nt] = __builtin_amdgcn_mfma_f32_16x16x32_bf16(al[mt], bh[nt], acc[mt][nt], 0,0,0);
          }
    }
    #pragma unroll
    for (int mt = 0; mt < 4; mt++)
      #pragma unroll
      for (int nt = 0; nt < 4; nt++)
        #pragma unroll
        for (int r = 0; r < 4; r++){
            int gr = m0 + wm + mt*16 + lq*4 + r;
            int gc = n0 + wn + nt*16 + lr;
            G[(size_t)gr*L + gc] = acc[mt][nt][r];
        }
}

// ---------------- similarity stencil: Y = 9-term diag window of G / norm ---------
__global__ void s1_kernel(const float* __restrict__ G, const float* __restrict__ rnorm,
                          float* __restrict__ Y){
    int Bc = blockIdx.x*256 + threadIdx.x;
    int A  = blockIdx.y;
    int i = A >> 6, j = A & 63, p = Bc >> 6, q = Bc & 63;
    float s = 0.f;
    #pragma unroll
    for (int di = -1; di <= 1; di++){
        if ((unsigned)(i+di) >= 64u || (unsigned)(p+di) >= 64u) continue;
        #pragma unroll
        for (int dj = -1; dj <= 1; dj++){
            if ((unsigned)(j+dj) >= 64u || (unsigned)(q+dj) >= 64u) continue;
            s += G[(size_t)(A + di*64 + dj)*L + (Bc + di*64 + dj)];
        }
    }
    Y[(size_t)A*L + Bc] = s * rnorm[Bc];
}

// ---------------- fuse: 3-term diagonal stencil in flat coords (incl. wrap) ------
__global__ void fuse_kernel(const float* __restrict__ X, float* __restrict__ O){
    int Bc = blockIdx.x*256 + threadIdx.x;
    int A  = blockIdx.y;
    float s = X[(size_t)A*L + Bc];
    if (A > 0   && Bc > 0  ) s += X[(size_t)(A-1)*L + (Bc-1)];
    if (A < L-1 && Bc < L-1) s += X[(size_t)(A+1)*L + (Bc+1)];
    O[(size_t)A*L + Bc] = s;
}

// ---------------- 4D transpose [i,j,p,q] -> [j,i,q,p] ----------------------------
__global__ void transp_kernel(const float* __restrict__ X, float* __restrict__ O){
    __shared__ float lds[64*65];
    int A = blockIdx.x, t = threadIdx.x;
    #pragma unroll
    for (int it = 0; it < 16; it++){
        int Bc = t + it*256; int p = Bc >> 6, q = Bc & 63;
        lds[p*65 + q] = X[(size_t)A*L + Bc];
    }
    __syncthreads();
    int Ap = (A & 63)*64 + (A >> 6);
    #pragma unroll
    for (int it = 0; it < 16; it++){
        int bp = t + it*256; int p = bp & 63, q = bp >> 6;
        O[(size_t)Ap*L + bp] = lds[p*65 + q];
    }
}

// ---------------- masked softmax over each row (transposed layout) ---------------
__global__ void softmax_kernel(const float* __restrict__ F, const float* __restrict__ mmT,
                               bf16* __restrict__ attn){
    int row = blockIdx.x, t = threadIdx.x;
    float z[16];
    float mx = -1e30f;
    #pragma unroll
    for (int i = 0; i < 16; i++){
        int col = t + i*256;
        float v = F[(size_t)row*L + col] * mmT[col] * 10.f;
        z[i] = v; mx = fmaxf(mx, v);
    }
    __shared__ float red[4], red2[4];
    #pragma unroll
    for (int o = 32; o > 0; o >>= 1) mx = fmaxf(mx, __shfl_down(mx, o));
    if ((t & 63) == 0) red[t >> 6] = mx;
    __syncthreads();
    mx = fmaxf(fmaxf(red[0], red[1]), fmaxf(red[2], red[3]));
    float sm = 0.f;
    #pragma unroll
    for (int i = 0; i < 16; i++){ z[i] = __expf(z[i] - mx); sm += z[i]; }
    #pragma unroll
    for (int o = 32; o > 0; o >>= 1) sm += __shfl_down(sm, o);
    if ((t & 63) == 0) red2[t >> 6] = sm;
    __syncthreads();
    sm = red2[0] + red2[1] + red2[2] + red2[3];
    float inv = 1.f / sm;
    #pragma unroll
    for (int i = 0; i < 16; i++){
        int col = t + i*256;
        attn[(size_t)row*L + col] = __float2bfloat16(z[i] * inv * mmT[col]);
    }
}

// ---------------- build 4 parity-class V matrices from attn ----------------------
__global__ void v4_kernel(const bf16* __restrict__ attn, bf16* __restrict__ V4){
    int kp = blockIdx.x*256 + threadIdx.x;   // k' = Q*64+P
    int mp = blockIdx.y;                      // m' = Y*64+X
    int X = mp & 63, Yv = mp >> 6, P = kp & 63, Q = kp >> 6;
    float val[3][3];
    #pragma unroll
    for (int u = -1; u <= 1; u++)
      #pragma unroll
      for (int w = -1; w <= 1; w++){
        float v = 0.f;
        if ((unsigned)(X-u) < 64u && (unsigned)(Yv-w) < 64u &&
            (unsigned)(P-u) < 64u && (unsigned)(Q-w) < 64u)
            v = __bfloat162float(attn[(size_t)((Yv-w)*64 + (X-u))*L + ((Q-w)*64 + (P-u))]);
        val[u+1][w+1] = v;
      }
    #pragma unroll
    for (int par = 0; par < 4; par++){
        int dx = par >> 1, dy = par & 1;
        int sx = 1 - 2*dx, sy = 1 - 2*dy;
        float v = val[1][1] + val[1+sx][1] + val[1][1+sy] + val[1+sx][1+sy];
        V4[(size_t)par*L*L + (size_t)mp*L + kp] = __float2bfloat16(v);
    }
}

// ---------------- paste GEMM: out = 0.25 * V4_par @ bpar_par ---------------------
__global__ __launch_bounds__(256) void gemm_paste(
        const bf16* __restrict__ V4, const bf16* __restrict__ bpar,
        float* __restrict__ out, int batch){
    __shared__ __align__(16) bf16 Ab[64][40];
    __shared__ __align__(16) bf16 Bb[192][40];
    int t = threadIdx.x;
    int par = blockIdx.y;
    int m0 = blockIdx.x * 64;
    const bf16* Am = V4   + (size_t)par*L*L;
    const bf16* Bm = bpar + (size_t)par*L*C;
    int wv = t >> 6, lane = t & 63, lr = lane & 15, lq = lane >> 4;
    f32x4 acc[12] = {};

    for (int kk = 0; kk < 128; kk++){
        int k0 = kk * 32;
        __syncthreads();
        { int row = t >> 2, kc = t & 3;
          *(uint4*)&Ab[row][kc*8] = *(const uint4*)(Am + (size_t)(m0+row)*L + k0 + kc*8); }
        #pragma unroll
        for (int i = 0; i < 24; i++){
            int e = i*256 + t; int k = e / 192, c2 = e - k*192;
            Bb[c2][k] = Bm[(size_t)(k0 + k)*C + c2];
        }
        __syncthreads();
        bf16x8 af = *(bf16x8*)&Ab[wv*16 + lr][lq*8];
        #pragma unroll
        for (int nt = 0; nt < 12; nt++){
            bf16x8 bfr = *(bf16x8*)&Bb[nt*16 + lr][lq*8];
            acc[nt] = __builtin_amdgcn_mfma_f32_16x16x32_bf16(af, bfr, acc[nt], 0,0,0);
        }
    }
    int dx = par >> 1, dy = par & 1;
    #pragma unroll
    for (int nt = 0; nt < 12; nt++)
      #pragma unroll
      for (int r = 0; r < 4; r++){
        int m = m0 + wv*16 + lq*4 + r;
        int X = m & 63, Yv = m >> 6;
        int x = 2*X + dx, y = 2*Yv + dy, c2 = nt*16 + lr;
        out[(size_t)((batch*HF + x)*HF + y)*C + c2] = 0.25f * acc[nt][r];
      }
}

// ---------------- host ----------------
extern "C" void kernel_launch(void* const* d_in, const int* in_sizes, int n_in,
                              void* d_out, int out_size, void* d_ws, size_t ws_size,
                              hipStream_t stream){
    const float* f    = (const float*)d_in[0];
    const float* b    = (const float*)d_in[1];
    const float* mask = (const float*)d_in[2];
    float* out = (float*)d_out;
    char* ws = (char*)d_ws;

    float* U    = (float*)(ws);                      // 64 MB
    float* Vb   = (float*)(ws + 67108864ull);        // 64 MB
    bf16*  attn = (bf16*) (ws + 134217728ull);       // 32 MB
    bf16*  V4   = (bf16*) (ws);                      // 128 MB (reuses U+Vb after softmax)
    char* ops = ws + 167772160ull;                   // operand area (~12.4 MB)
    bf16* fdh  = (bf16*)(ops);
    bf16* fdl  = (bf16*)(ops + 1*1572864ull);
    bf16* bdh  = (bf16*)(ops + 2*1572864ull);
    bf16* bdl  = (bf16*)(ops + 3*1572864ull);
    bf16* bpar = (bf16*)(ops + 4*1572864ull);        // 4 x 1.5 MB
    float* ss    = (float*)(ops + 8*1572864ull);
    float* rnorm = (float*)(ops + 8*1572864ull + 16384);
    float* mmT   = (float*)(ops + 8*1572864ull + 32768);

    for (int batch = 0; batch < 2; batch++){
        prep_kernel  <<<dim3(4096),    dim3(192), 0, stream>>>(f, b, fdh, fdl, bdh, bdl, bpar, ss, batch);
        normmm_kernel<<<dim3(16),      dim3(256), 0, stream>>>(mask, ss, rnorm, mmT);
        gemm_g       <<<dim3(32,32),   dim3(256), 0, stream>>>(fdh, fdl, bdh, bdl, U);
        s1_kernel    <<<dim3(16,4096), dim3(256), 0, stream>>>(U, rnorm, Vb);
        fuse_kernel  <<<dim3(16,4096), dim3(256), 0, stream>>>(Vb, U);
        transp_kernel<<<dim3(4096),    dim3(256), 0, stream>>>(U, Vb);
        fuse_kernel  <<<dim3(16,4096), dim3(256), 0, stream>>>(Vb, U);
        softmax_kernel<<<dim3(4096),   dim3(256), 0, stream>>>(U, mmT, attn);
        v4_kernel    <<<dim3(16,4096), dim3(256), 0, stream>>>(attn, V4);
        gemm_paste   <<<dim3(64,4),    dim3(256), 0, stream>>>(V4, bpar, out, batch);
    }
}

// Round 2
// 581.730 us; speedup vs baseline: 1.7647x; 1.7647x over previous
//
#include <hip/hip_runtime.h>
#include <hip/hip_bf16.h>

typedef __hip_bfloat16 bf16;
typedef short bf16x8 __attribute__((ext_vector_type(8)));
typedef short short4v __attribute__((ext_vector_type(4)));
typedef float f32x4 __attribute__((ext_vector_type(4)));

struct __attribute__((packed, aligned(4))) uf4 { f32x4 v; };
struct __attribute__((packed, aligned(2))) us4 { short4v v; };

constexpr int C  = 192;
constexpr int HF = 128;
constexpr int L  = 4096;          // 64*64
constexpr long LL = (long)L * L;

__device__ inline float bf2f(short s){
    union { unsigned u; float f; } x; x.u = ((unsigned)(unsigned short)s) << 16;
    return x.f;
}
__device__ inline short f2bf_s(float f){
    bf16 h = __float2bfloat16(f);
    return *reinterpret_cast<short*>(&h);
}

// ---------------- prep: downsample, bf16 split, parity images, ss ----------------
__global__ void prep_kernel(const float* __restrict__ f, const float* __restrict__ b,
                            bf16* __restrict__ fdh, bf16* __restrict__ fdl,
                            bf16* __restrict__ bdh, bf16* __restrict__ bdl,
                            bf16* __restrict__ bpar, float* __restrict__ ss, int batch){
    int pos = blockIdx.x;            // p*64+q
    int p = pos >> 6, q = pos & 63;
    int c = threadIdx.x;             // 0..191
    const float* fb = f + (size_t)batch * HF * HF * C;
    const float* bb = b + (size_t)batch * HF * HF * C;

    float fv = fb[((2*p)*HF + 2*q)*C + c];
    bf16 fh = __float2bfloat16(fv);
    fdh[(size_t)pos*C + c] = fh;
    fdl[(size_t)pos*C + c] = __float2bfloat16(fv - __bfloat162float(fh));

    float b00 = 0.f;
    #pragma unroll
    for (int dx = 0; dx < 2; dx++)
      #pragma unroll
      for (int dy = 0; dy < 2; dy++){
        float bv = bb[((2*p+dx)*HF + (2*q+dy))*C + c];
        int par = dx*2 + dy;
        bpar[((size_t)par*L + pos)*C + c] = __float2bfloat16(bv);   // [par][k=p*64+q][c]
        if (par == 0){
            b00 = bv;
            bf16 bh = __float2bfloat16(bv);
            bdh[(size_t)pos*C + c] = bh;
            bdl[(size_t)pos*C + c] = __float2bfloat16(bv - __bfloat162float(bh));
        }
      }

    __shared__ float red[3];
    float v = b00 * b00;
    #pragma unroll
    for (int o = 32; o > 0; o >>= 1) v += __shfl_down(v, o);
    if ((threadIdx.x & 63) == 0) red[threadIdx.x >> 6] = v;
    __syncthreads();
    if (threadIdx.x == 0) ss[pos] = red[0] + red[1] + red[2];
}

// ---------------- norm (3x3 window of ss) and mask mm (original layout) ----------
__global__ void normmm_kernel(const float* __restrict__ mask, const float* __restrict__ ss,
                              float* __restrict__ rnorm, float* __restrict__ mmv){
    int pos = blockIdx.x*256 + threadIdx.x;
    int p = pos >> 6, q = pos & 63;
    float s = 0.f, ms = 0.f;
    #pragma unroll
    for (int di = -1; di <= 1; di++)
      #pragma unroll
      for (int dj = -1; dj <= 1; dj++){
        int pp = p + di, qq = q + dj;
        if ((unsigned)pp < 64u && (unsigned)qq < 64u){
            s  += ss[pp*64 + qq];
            ms += mask[(2*pp)*HF + 2*qq];
        }
      }
    float n = fmaxf(sqrtf(s), 1e-4f);
    rnorm[pos] = 1.f / n;
    mmv[pos] = (ms == 0.f) ? 1.f : 0.f;
}

// ---------------- repack bpar[par][k][c] -> bparT[par][c][k] ---------------------
__global__ void repack_kernel(const bf16* __restrict__ bpar, bf16* __restrict__ bparT){
    __shared__ bf16 lds[64][66];
    int c0 = blockIdx.x * 64;        // 0..2  -> c tile
    int k0 = blockIdx.y * 64;        // 0..63 -> k tile
    int par = blockIdx.z;
    const bf16* src = bpar + (size_t)par*L*C;
    bf16* dst = bparT + (size_t)par*C*L;
    int t = threadIdx.x;
    #pragma unroll
    for (int it = 0; it < 16; it++){
        int e = t + it*256; int cc = e & 63, kk = e >> 6;
        lds[kk][cc] = src[(size_t)(k0+kk)*C + c0 + cc];
    }
    __syncthreads();
    #pragma unroll
    for (int it = 0; it < 16; it++){
        int e = t + it*256; int kk = e & 63, cc = e >> 6;
        dst[(size_t)(c0+cc)*L + k0 + kk] = lds[kk][cc];
    }
}

// ---------------- Gram GEMM: G[a,b] = sum_c fd[a,c]*bd[b,c], split-bf16 ----------
__global__ __launch_bounds__(256) void gemm_g(
        const bf16* __restrict__ fdh, const bf16* __restrict__ fdl,
        const bf16* __restrict__ bdh, const bf16* __restrict__ bdl,
        float* __restrict__ G){
    __shared__ __align__(16) bf16 Ah[128][40], Al[128][40], Bh[128][40], Bl[128][40];
    int t = threadIdx.x;
    int m0 = blockIdx.y * 128, n0 = blockIdx.x * 128;
    int wv = t >> 6, lane = t & 63, lr = lane & 15, lq = lane >> 4;
    int wm = (wv >> 1) * 64, wn = (wv & 1) * 64;
    f32x4 acc[4][4] = {};

    for (int kk = 0; kk < 6; kk++){
        int k0 = kk * 32;
        __syncthreads();
        #pragma unroll
        for (int r = 0; r < 2; r++){
            int e = r*256 + t; int row = e >> 2, kc = e & 3;
            *(uint4*)&Ah[row][kc*8] = *(const uint4*)(fdh + (size_t)(m0+row)*C + k0 + kc*8);
            *(uint4*)&Al[row][kc*8] = *(const uint4*)(fdl + (size_t)(m0+row)*C + k0 + kc*8);
            *(uint4*)&Bh[row][kc*8] = *(const uint4*)(bdh + (size_t)(n0+row)*C + k0 + kc*8);
            *(uint4*)&Bl[row][kc*8] = *(const uint4*)(bdl + (size_t)(n0+row)*C + k0 + kc*8);
        }
        __syncthreads();
        bf16x8 ah[4], al[4], bh[4], bl[4];
        #pragma unroll
        for (int mt = 0; mt < 4; mt++){
            ah[mt] = *(bf16x8*)&Ah[wm + mt*16 + lr][lq*8];
            al[mt] = *(bf16x8*)&Al[wm + mt*16 + lr][lq*8];
        }
        #pragma unroll
        for (int nt = 0; nt < 4; nt++){
            bh[nt] = *(bf16x8*)&Bh[wn + nt*16 + lr][lq*8];
            bl[nt] = *(bf16x8*)&Bl[wn + nt*16 + lr][lq*8];
        }
        #pragma unroll
        for (int mt = 0; mt < 4; mt++)
          #pragma unroll
          for (int nt = 0; nt < 4; nt++){
            acc[mt][nt] = __builtin_amdgcn_mfma_f32_16x16x32_bf16(ah[mt], bh[nt], acc[mt][nt], 0,0,0);
            acc[mt][nt] = __builtin_amdgcn_mfma_f32_16x16x32_bf16(ah[mt], bl[nt], acc[mt][nt], 0,0,0);
            acc[mt][nt] = __builtin_amdgcn_mfma_f32_16x16x32_bf16(al[mt], bh[nt], acc[mt][nt], 0,0,0);
          }
    }
    #pragma unroll
    for (int mt = 0; mt < 4; mt++)
      #pragma unroll
      for (int nt = 0; nt < 4; nt++)
        #pragma unroll
        for (int r = 0; r < 4; r++){
            int gr = m0 + wm + mt*16 + lq*4 + r;
            int gc = n0 + wn + nt*16 + lr;
            G[(size_t)gr*L + gc] = acc[mt][nt][r];
        }
}

// ---------------- fused s1 (9-tap) + fuse1 (3-tap diag): 15 diag offsets ---------
__global__ void s1f_kernel(const float* __restrict__ G, const float* __restrict__ rnorm,
                           float* __restrict__ F1){
    int A  = blockIdx.y;
    int B0 = (blockIdx.x*256 + threadIdx.x)*4;
    long base = (long)A*L + B0;
    f32x4 g[3][5];
    #pragma unroll
    for (int di = 0; di < 3; di++)
      #pragma unroll
      for (int s = 0; s < 5; s++){
        long idx = base + (long)((di-1)*64 + (s-2)) * (L+1);
        idx = idx < 0 ? 0 : idx;
        idx = idx > (LL-4) ? (LL-4) : idx;
        g[di][s] = ((const uf4*)(G + idx))->v;
      }
    int i = A >> 6, j = A & 63;
    int p0 = B0 >> 6, q0 = B0 & 63;
    f32x4 acc = {0.f,0.f,0.f,0.f};
    #pragma unroll
    for (int d = -1; d <= 1; d++){
        bool fvA = (unsigned)(A+d) < (unsigned)L;
        int jd = j + d; int i1 = i + (jd >> 6); int j1 = jd & 63;
        #pragma unroll
        for (int e = 0; e < 4; e++){
            int Bq = B0 + e;
            bool fvB = (unsigned)(Bq + d) < (unsigned)L;
            int qd = q0 + e + d; int p1 = p0 + (qd >> 6); int q1 = qd & 63;
            int rb = Bq + d; rb = rb < 0 ? 0 : (rb > L-1 ? L-1 : rb);
            float wd = (fvA && fvB) ? rnorm[rb] : 0.f;
            float a = 0.f;
            #pragma unroll
            for (int di = -1; di <= 1; di++){
                bool rok = ((unsigned)(i1+di) < 64u) && ((unsigned)(p1+di) < 64u);
                #pragma unroll
                for (int dj = -1; dj <= 1; dj++){
                    bool cok = ((unsigned)(j1+dj) < 64u) && ((unsigned)(q1+dj) < 64u);
                    a += (rok && cok) ? g[di+1][d+dj+2][e] : 0.f;
                }
            }
            acc[e] += wd * a;
        }
    }
    *(f32x4*)(F1 + base) = acc;
}

// -------- fuse2 (transposed-flat diag stencil mapped to original layout) + softmax
__global__ void fsoft_kernel(const float* __restrict__ F1, const float* __restrict__ mmv,
                             bf16* __restrict__ attn){
    int A = blockIdx.x, t = threadIdx.x;
    int i = A >> 6, j = A & 63;
    bool pok = A < L-1, mok = A > 0;
    int rowp = (i < 63) ? A + 64 : j + 1;          // transposed-flat +1 mapped back
    int rowm = (i > 0)  ? A - 64 : 63*64 + j - 1;  // transposed-flat -1 mapped back
    float z[16]; float mx = -1e30f;
    #pragma unroll
    for (int it = 0; it < 16; it++){
        int Bq = t + it*256;
        int p = Bq >> 6, q = Bq & 63;
        float v = F1[(size_t)A*L + Bq];
        if (pok && Bq < L-1){
            int colp = (p < 63) ? Bq + 64 : q + 1;
            v += F1[(size_t)rowp*L + colp];
        }
        if (mok && Bq > 0){
            int colm = (p > 0) ? Bq - 64 : 63*64 + q - 1;
            v += F1[(size_t)rowm*L + colm];
        }
        v = v * mmv[Bq] * 10.f;
        z[it] = v; mx = fmaxf(mx, v);
    }
    __shared__ float red[4];
    #pragma unroll
    for (int o = 32; o > 0; o >>= 1) mx = fmaxf(mx, __shfl_down(mx, o));
    if ((t & 63) == 0) red[t >> 6] = mx;
    __syncthreads();
    mx = fmaxf(fmaxf(red[0], red[1]), fmaxf(red[2], red[3]));
    float sm = 0.f;
    #pragma unroll
    for (int it = 0; it < 16; it++){ z[it] = __expf(z[it] - mx); sm += z[it]; }
    #pragma unroll
    for (int o = 32; o > 0; o >>= 1) sm += __shfl_down(sm, o);
    __syncthreads();
    if ((t & 63) == 0) red[t >> 6] = sm;
    __syncthreads();
    sm = red[0] + red[1] + red[2] + red[3];
    float inv = 1.f / sm;
    #pragma unroll
    for (int it = 0; it < 16; it++){
        int Bq = t + it*256;
        attn[(size_t)A*L + Bq] = __float2bfloat16(z[it] * inv * mmv[Bq]);
    }
}

// ---------------- build 4 parity-class V matrices from attn (vec x4) -------------
__global__ void v4_kernel(const bf16* __restrict__ attn, bf16* __restrict__ V4){
    int k0 = (blockIdx.x*256 + threadIdx.x)*4;
    int m  = blockIdx.y;
    int X = m >> 6, Yv = m & 63, P = k0 >> 6, Q0 = k0 & 63;
    float val[3][3][4];
    #pragma unroll
    for (int u = -1; u <= 1; u++)
      #pragma unroll
      for (int w = -1; w <= 1; w++){
        long idx = (long)m*L + k0 - (long)(64*u + w)*(L+1);
        idx = idx < 0 ? 0 : idx;
        idx = idx > (LL-4) ? (LL-4) : idx;
        short4v sv = ((const us4*)(attn + idx))->v;
        bool rok = ((unsigned)(X-u) < 64u) && ((unsigned)(Yv-w) < 64u) && ((unsigned)(P-u) < 64u);
        #pragma unroll
        for (int e = 0; e < 4; e++){
            bool ok = rok && ((unsigned)(Q0+e-w) < 64u);
            val[u+1][w+1][e] = ok ? bf2f(sv[e]) : 0.f;
        }
      }
    #pragma unroll
    for (int par = 0; par < 4; par++){
        int sx = 1 - 2*(par>>1), sy = 1 - 2*(par&1);
        short4v o;
        #pragma unroll
        for (int e = 0; e < 4; e++){
            float v = val[1][1][e] + val[1+sx][1][e] + val[1][1+sy][e] + val[1+sx][1+sy][e];
            o[e] = f2bf_s(v);
        }
        *(short4v*)(V4 + (size_t)par*L*(size_t)L + (size_t)m*L + k0) = o;
    }
}

// ---------------- paste GEMM: out = 0.25 * V4_par @ bparT_par^T ------------------
__global__ __launch_bounds__(256) void gemm_paste(
        const bf16* __restrict__ V4, const bf16* __restrict__ bparT,
        float* __restrict__ out, int batch){
    __shared__ __align__(16) bf16 Ab[64][72];
    __shared__ __align__(16) bf16 Bb[192][72];
    int t = threadIdx.x;
    int par = blockIdx.y;
    int m0 = blockIdx.x * 64;
    const bf16* Am = V4    + (size_t)par*L*(size_t)L;
    const bf16* Bm = bparT + (size_t)par*C*L;
    int wv = t >> 6, lane = t & 63, lr = lane & 15, lq = lane >> 4;
    f32x4 acc[4][3] = {};

    for (int kk = 0; kk < 64; kk++){
        int k0 = kk * 64;
        __syncthreads();
        #pragma unroll
        for (int r = 0; r < 2; r++){
            int e = r*256 + t; int row = e >> 3, kc = e & 7;
            *(uint4*)&Ab[row][kc*8] = *(const uint4*)(Am + (size_t)(m0+row)*L + k0 + kc*8);
        }
        #pragma unroll
        for (int r = 0; r < 6; r++){
            int e = r*256 + t; int c2 = e >> 3, kc = e & 7;
            *(uint4*)&Bb[c2][kc*8] = *(const uint4*)(Bm + (size_t)c2*L + k0 + kc*8);
        }
        __syncthreads();
        #pragma unroll
        for (int kk2 = 0; kk2 < 2; kk2++){
            bf16x8 a[4], bfr[3];
            #pragma unroll
            for (int mt = 0; mt < 4; mt++)
                a[mt] = *(bf16x8*)&Ab[mt*16 + lr][kk2*32 + lq*8];
            #pragma unroll
            for (int nt = 0; nt < 3; nt++)
                bfr[nt] = *(bf16x8*)&Bb[wv*48 + nt*16 + lr][kk2*32 + lq*8];
            #pragma unroll
            for (int mt = 0; mt < 4; mt++)
              #pragma unroll
              for (int nt = 0; nt < 3; nt++)
                acc[mt][nt] = __builtin_amdgcn_mfma_f32_16x16x32_bf16(a[mt], bfr[nt], acc[mt][nt], 0,0,0);
        }
    }
    int dx = par >> 1, dy = par & 1;
    #pragma unroll
    for (int mt = 0; mt < 4; mt++)
      #pragma unroll
      for (int nt = 0; nt < 3; nt++)
        #pragma unroll
        for (int r = 0; r < 4; r++){
            int m = m0 + mt*16 + lq*4 + r;
            int X = m >> 6, Yv = m & 63;
            int x = 2*X + dx, y = 2*Yv + dy, c2 = wv*48 + nt*16 + lr;
            out[(size_t)((batch*HF + x)*HF + y)*C + c2] = 0.25f * acc[mt][nt][r];
        }
}

// ---------------- host ----------------
extern "C" void kernel_launch(void* const* d_in, const int* in_sizes, int n_in,
                              void* d_out, int out_size, void* d_ws, size_t ws_size,
                              hipStream_t stream){
    const float* f    = (const float*)d_in[0];
    const float* b    = (const float*)d_in[1];
    const float* mask = (const float*)d_in[2];
    float* out = (float*)d_out;
    char* ws = (char*)d_ws;

    float* G    = (float*)(ws);                      //  0 .. 64 MB
    float* F1   = (float*)(ws + 67108864ull);        // 64 .. 128 MB
    bf16*  attn = (bf16*) (ws + 134217728ull);       // 128 .. 160 MB
    bf16*  bpar = (bf16*) (ws + 134217728ull);       // overlays attn (dead before attn written)
    bf16*  V4   = (bf16*) (ws);                      // 0 .. 128 MB (overlays G+F1 after softmax)
    char* ops = ws + 167772160ull;                   // operand area
    bf16* fdh   = (bf16*)(ops);
    bf16* fdl   = (bf16*)(ops + 1*1572864ull);
    bf16* bdh   = (bf16*)(ops + 2*1572864ull);
    bf16* bdl   = (bf16*)(ops + 3*1572864ull);
    bf16* bparT = (bf16*)(ops + 4*1572864ull);       // 6.29 MB: [4][192][4096]
    float* ss    = (float*)(ops + 4*1572864ull + 6291456ull);
    float* rnorm = (float*)(ops + 4*1572864ull + 6291456ull + 16384);
    float* mmv   = (float*)(ops + 4*1572864ull + 6291456ull + 32768);

    for (int batch = 0; batch < 2; batch++){
        prep_kernel  <<<dim3(4096),     dim3(192), 0, stream>>>(f, b, fdh, fdl, bdh, bdl, bpar, ss, batch);
        normmm_kernel<<<dim3(16),       dim3(256), 0, stream>>>(mask, ss, rnorm, mmv);
        repack_kernel<<<dim3(3,64,4),   dim3(256), 0, stream>>>(bpar, bparT);
        gemm_g       <<<dim3(32,32),    dim3(256), 0, stream>>>(fdh, fdl, bdh, bdl, G);
        s1f_kernel   <<<dim3(4,4096),   dim3(256), 0, stream>>>(G, rnorm, F1);
        fsoft_kernel <<<dim3(4096),     dim3(256), 0, stream>>>(F1, mmv, attn);
        v4_kernel    <<<dim3(4,4096),   dim3(256), 0, stream>>>(attn, V4);
        gemm_paste   <<<dim3(64,4),     dim3(256), 0, stream>>>(V4, bparT, out, batch);
    }
}

// Round 3
// 510.756 us; speedup vs baseline: 2.0100x; 1.1390x over previous
//
#include <hip/hip_runtime.h>
#include <hip/hip_bf16.h>

typedef __hip_bfloat16 bf16;
typedef short bf16x8 __attribute__((ext_vector_type(8)));
typedef short short4v __attribute__((ext_vector_type(4)));
typedef float f32x4 __attribute__((ext_vector_type(4)));

struct __attribute__((packed, aligned(4))) uf4 { f32x4 v; };
struct __attribute__((packed, aligned(4))) uu4 { uint4 v; };

constexpr int C  = 192;
constexpr int HF = 128;
constexpr int L  = 4096;          // 64*64

__device__ inline float u2f(unsigned u){
    union { unsigned u; float f; } x; x.u = u; return x.f;
}
__device__ inline short f2bf_s(float f){
    bf16 h = __float2bfloat16(f);
    return *reinterpret_cast<short*>(&h);
}

// ---------------- prep: downsample, bf16 split, parity images, ss ----------------
__global__ void prep_kernel(const float* __restrict__ f, const float* __restrict__ b,
                            bf16* __restrict__ fdh, bf16* __restrict__ fdl,
                            bf16* __restrict__ bdh, bf16* __restrict__ bdl,
                            bf16* __restrict__ bpar, float* __restrict__ ss, int batch){
    int pos = blockIdx.x;            // p*64+q
    int p = pos >> 6, q = pos & 63;
    int c = threadIdx.x;             // 0..191
    const float* fb = f + (size_t)batch * HF * HF * C;
    const float* bb = b + (size_t)batch * HF * HF * C;

    float fv = fb[((2*p)*HF + 2*q)*C + c];
    bf16 fh = __float2bfloat16(fv);
    fdh[(size_t)pos*C + c] = fh;
    fdl[(size_t)pos*C + c] = __float2bfloat16(fv - __bfloat162float(fh));

    float b00 = 0.f;
    #pragma unroll
    for (int dx = 0; dx < 2; dx++)
      #pragma unroll
      for (int dy = 0; dy < 2; dy++){
        float bv = bb[((2*p+dx)*HF + (2*q+dy))*C + c];
        int par = dx*2 + dy;
        bpar[((size_t)par*L + pos)*C + c] = __float2bfloat16(bv);   // [par][k=p*64+q][c]
        if (par == 0){
            b00 = bv;
            bf16 bh = __float2bfloat16(bv);
            bdh[(size_t)pos*C + c] = bh;
            bdl[(size_t)pos*C + c] = __float2bfloat16(bv - __bfloat162float(bh));
        }
      }

    __shared__ float red[3];
    float v = b00 * b00;
    #pragma unroll
    for (int o = 32; o > 0; o >>= 1) v += __shfl_down(v, o);
    if ((threadIdx.x & 63) == 0) red[threadIdx.x >> 6] = v;
    __syncthreads();
    if (threadIdx.x == 0) ss[pos] = red[0] + red[1] + red[2];
}

// ---------------- norm (3x3 window of ss) and mask mm ----------------------------
__global__ void normmm_kernel(const float* __restrict__ mask, const float* __restrict__ ss,
                              float* __restrict__ rnorm, float* __restrict__ mmv){
    int pos = blockIdx.x*256 + threadIdx.x;
    int p = pos >> 6, q = pos & 63;
    float s = 0.f, ms = 0.f;
    #pragma unroll
    for (int di = -1; di <= 1; di++)
      #pragma unroll
      for (int dj = -1; dj <= 1; dj++){
        int pp = p + di, qq = q + dj;
        if ((unsigned)pp < 64u && (unsigned)qq < 64u){
            s  += ss[pp*64 + qq];
            ms += mask[(2*pp)*HF + 2*qq];
        }
      }
    float n = fmaxf(sqrtf(s), 1e-4f);
    rnorm[pos] = 1.f / n;
    mmv[pos] = (ms == 0.f) ? 1.f : 0.f;
}

// ---------------- repack bpar[par][k][c] -> bparT[par][c][k] ---------------------
__global__ void repack_kernel(const bf16* __restrict__ bpar, bf16* __restrict__ bparT){
    __shared__ bf16 lds[64][66];
    int c0 = blockIdx.x * 64;
    int k0 = blockIdx.y * 64;
    int par = blockIdx.z;
    const bf16* src = bpar + (size_t)par*L*C;
    bf16* dst = bparT + (size_t)par*C*L;
    int t = threadIdx.x;
    #pragma unroll
    for (int it = 0; it < 16; it++){
        int e = t + it*256; int cc = e & 63, kk = e >> 6;
        lds[kk][cc] = src[(size_t)(k0+kk)*C + c0 + cc];
    }
    __syncthreads();
    #pragma unroll
    for (int it = 0; it < 16; it++){
        int e = t + it*256; int kk = e & 63, cc = e >> 6;
        dst[(size_t)(c0+cc)*L + k0 + kk] = lds[kk][cc];
    }
}

// ---------------- Gram GEMM: G[a,b] = sum_c fd[a,c]*bd[b,c], split-bf16 ----------
__global__ __launch_bounds__(256) void gemm_g(
        const bf16* __restrict__ fdh, const bf16* __restrict__ fdl,
        const bf16* __restrict__ bdh, const bf16* __restrict__ bdl,
        float* __restrict__ G){
    __shared__ __align__(16) bf16 Ah[128][40], Al[128][40], Bh[128][40], Bl[128][40];
    int t = threadIdx.x;
    int m0 = blockIdx.y * 128, n0 = blockIdx.x * 128;
    int wv = t >> 6, lane = t & 63, lr = lane & 15, lq = lane >> 4;
    int wm = (wv >> 1) * 64, wn = (wv & 1) * 64;
    f32x4 acc[4][4] = {};

    for (int kk = 0; kk < 6; kk++){
        int k0 = kk * 32;
        __syncthreads();
        #pragma unroll
        for (int r = 0; r < 2; r++){
            int e = r*256 + t; int row = e >> 2, kc = e & 3;
            *(uint4*)&Ah[row][kc*8] = *(const uint4*)(fdh + (size_t)(m0+row)*C + k0 + kc*8);
            *(uint4*)&Al[row][kc*8] = *(const uint4*)(fdl + (size_t)(m0+row)*C + k0 + kc*8);
            *(uint4*)&Bh[row][kc*8] = *(const uint4*)(bdh + (size_t)(n0+row)*C + k0 + kc*8);
            *(uint4*)&Bl[row][kc*8] = *(const uint4*)(bdl + (size_t)(n0+row)*C + k0 + kc*8);
        }
        __syncthreads();
        bf16x8 ah[4], al[4], bh[4], bl[4];
        #pragma unroll
        for (int mt = 0; mt < 4; mt++){
            ah[mt] = *(bf16x8*)&Ah[wm + mt*16 + lr][lq*8];
            al[mt] = *(bf16x8*)&Al[wm + mt*16 + lr][lq*8];
        }
        #pragma unroll
        for (int nt = 0; nt < 4; nt++){
            bh[nt] = *(bf16x8*)&Bh[wn + nt*16 + lr][lq*8];
            bl[nt] = *(bf16x8*)&Bl[wn + nt*16 + lr][lq*8];
        }
        #pragma unroll
        for (int mt = 0; mt < 4; mt++)
          #pragma unroll
          for (int nt = 0; nt < 4; nt++){
            acc[mt][nt] = __builtin_amdgcn_mfma_f32_16x16x32_bf16(ah[mt], bh[nt], acc[mt][nt], 0,0,0);
            acc[mt][nt] = __builtin_amdgcn_mfma_f32_16x16x32_bf16(ah[mt], bl[nt], acc[mt][nt], 0,0,0);
            acc[mt][nt] = __builtin_amdgcn_mfma_f32_16x16x32_bf16(al[mt], bh[nt], acc[mt][nt], 0,0,0);
          }
    }
    #pragma unroll
    for (int mt = 0; mt < 4; mt++)
      #pragma unroll
      for (int nt = 0; nt < 4; nt++)
        #pragma unroll
        for (int r = 0; r < 4; r++){
            int gr = m0 + wm + mt*16 + lq*4 + r;
            int gc = n0 + wn + nt*16 + lr;
            G[(size_t)gr*L + gc] = acc[mt][nt][r];
        }
}

// ---------------- fused s1 (9-tap) + fuse1 (3-tap diag), 8 outputs/thread --------
__global__ __launch_bounds__(256) void s1f_kernel(const float* __restrict__ G,
                                                  const float* __restrict__ rnorm,
                                                  float* __restrict__ F1){
    int A = blockIdx.y;
    int tB0 = (blockIdx.x*256 + (int)threadIdx.x) * 8;
    const float* gA = G + (size_t)A*L + tB0;

    bool fvA[3]; bool rowOK[3][3]; bool colOK[3][3];
    #pragma unroll
    for (int dd = 0; dd < 3; dd++){
        int A1 = A + dd - 1;
        fvA[dd] = (unsigned)A1 < (unsigned)L;
        int i1 = A1 >> 6, j1 = A1 & 63;
        #pragma unroll
        for (int k = 0; k < 3; k++){
            rowOK[dd][k] = (unsigned)(i1 + k - 1) < 64u;
            colOK[dd][k] = (unsigned)(j1 + k - 1) < 64u;
        }
    }

    float S[3][8];
    #pragma unroll
    for (int dd = 0; dd < 3; dd++)
      #pragma unroll
      for (int e = 0; e < 8; e++) S[dd][e] = 0.f;

    #pragma unroll
    for (int di = 0; di < 3; di++){
        float g[5][8];
        #pragma unroll
        for (int s = 0; s < 5; s++){
            const float* p = gA + (long)((di-1)*64 + (s-2)) * (long)(L+1);
            *(f32x4*)&g[s][0] = ((const uf4*)p)->v;
            *(f32x4*)&g[s][4] = ((const uf4*)(p+4))->v;
        }
        #pragma unroll
        for (int dd = 0; dd < 3; dd++){
            const int d = dd - 1;
            #pragma unroll
            for (int e = 0; e < 8; e++){
                int B1 = tB0 + e + d;
                int p1 = B1 >> 6, q1 = B1 & 63;
                bool rm = rowOK[dd][di] && ((unsigned)(p1 + di - 1) < 64u);
                float r = 0.f;
                #pragma unroll
                for (int dj = 0; dj < 3; dj++){
                    bool cm = colOK[dd][dj] && ((unsigned)(q1 + dj - 1) < 64u);
                    r += cm ? g[d + dj + 1][e] : 0.f;
                }
                S[dd][e] += rm ? r : 0.f;
            }
        }
    }

    float rn[12];
    const float* rp = rnorm + tB0 - 2;
    *(f32x4*)&rn[0] = ((const uf4*)rp)->v;
    *(f32x4*)&rn[4] = ((const uf4*)(rp+4))->v;
    *(f32x4*)&rn[8] = ((const uf4*)(rp+8))->v;

    float acc[8];
    #pragma unroll
    for (int e = 0; e < 8; e++){
        float a = 0.f;
        #pragma unroll
        for (int dd = 0; dd < 3; dd++){
            const int d = dd - 1;
            int B1 = tB0 + e + d;
            bool ok = fvA[dd] && ((unsigned)B1 < (unsigned)L);
            float wd = ok ? rn[e + d + 2] : 0.f;
            a += wd * S[dd][e];
        }
        acc[e] = a;
    }
    float* o = F1 + (size_t)A*L + tB0;
    *(f32x4*)(o)     = *(f32x4*)&acc[0];
    *(f32x4*)(o + 4) = *(f32x4*)&acc[4];
}

// -------- fuse2 (3-tap, transposed-flat wrap) + mask + softmax, vectorized -------
__global__ __launch_bounds__(256) void fsoft_kernel(const float* __restrict__ F1,
                                                    const float* __restrict__ mmv,
                                                    bf16* __restrict__ attn){
    int A = blockIdx.x, t = threadIdx.x;
    int i = A >> 6, j = A & 63;
    bool pok = A < L-1, mok = A > 0;
    int rowp = (i < 63) ? A + 64 : j + 1;
    int rowm = (i > 0)  ? A - 64 : 63*64 + j - 1;
    const float* FA = F1 + (size_t)A*L;
    const float* FP = F1 + (size_t)rowp*L;
    const float* FM = F1 + (size_t)rowm*L;

    float z[16]; float mx = -1e30f;
    #pragma unroll
    for (int it = 0; it < 4; it++){
        int b0 = (it*256 + t)*4;
        int p = b0 >> 6, q0 = b0 & 63;
        f32x4 v  = *(const f32x4*)(FA + b0);
        f32x4 mv = *(const f32x4*)(mmv + b0);
        f32x4 tp, tm;
        if (p < 63) tp = ((const uf4*)(FP + b0 + 64))->v;
        else        tp = ((const uf4*)(FP + q0 + 1))->v;
        if (p > 0)  tm = ((const uf4*)(FM + b0 - 64))->v;
        else        tm = ((const uf4*)(FM + 63*64 + q0 - 1))->v;
        #pragma unroll
        for (int e = 0; e < 4; e++){
            int Bq = b0 + e;
            float val = v[e];
            if (pok && Bq < L-1) val += tp[e];
            if (mok && Bq > 0)   val += tm[e];
            val = val * mv[e] * 10.f;
            z[it*4+e] = val; mx = fmaxf(mx, val);
        }
    }
    __shared__ float red[4];
    #pragma unroll
    for (int o = 32; o > 0; o >>= 1) mx = fmaxf(mx, __shfl_down(mx, o));
    if ((t & 63) == 0) red[t >> 6] = mx;
    __syncthreads();
    mx = fmaxf(fmaxf(red[0], red[1]), fmaxf(red[2], red[3]));
    float sm = 0.f;
    #pragma unroll
    for (int it = 0; it < 16; it++){ z[it] = __expf(z[it] - mx); sm += z[it]; }
    #pragma unroll
    for (int o = 32; o > 0; o >>= 1) sm += __shfl_down(sm, o);
    __syncthreads();
    if ((t & 63) == 0) red[t >> 6] = sm;
    __syncthreads();
    sm = red[0] + red[1] + red[2] + red[3];
    float inv = 1.f / sm;
    bf16* aA = attn + (size_t)A*L;
    #pragma unroll
    for (int it = 0; it < 4; it++){
        int b0 = (it*256 + t)*4;
        f32x4 mv = *(const f32x4*)(mmv + b0);
        short sv[4];
        #pragma unroll
        for (int e = 0; e < 4; e++)
            sv[e] = f2bf_s(z[it*4+e] * inv * mv[e]);
        *(short4v*)(aA + b0) = *(short4v*)&sv[0];
    }
}

// ---------------- fused v4 + paste GEMM ------------------------------------------
__global__ __launch_bounds__(256) void gemm_paste(
        const bf16* __restrict__ attn, const bf16* __restrict__ bparT,
        float* __restrict__ out, int batch){
    __shared__ __align__(16) bf16 Ab[32][72];
    __shared__ __align__(16) bf16 Bb[192][72];
    int t = threadIdx.x;
    int par = blockIdx.y;
    int m0 = blockIdx.x * 32;
    int dx = par >> 1, dy = par & 1;
    int sx = 1 - 2*dx, sy = 1 - 2*dy;
    const bf16* Bm = bparT + (size_t)par*C*L;
    int wv = t >> 6, lane = t & 63, lr = lane & 15, lq = lane >> 4;

    int arow = t >> 3, acol = (t & 7) * 8;
    int m = m0 + arow; int X = m >> 6, Yv = m & 63;
    bool r2 = (unsigned)(X - sx) < 64u;
    bool r3 = (unsigned)(Yv - sy) < 64u;
    bool r4 = r2 && r3;
    const bf16* row1 = attn + (size_t)m*L;
    const bf16* row2 = row1 - (long)(64*sx) * (long)(L+1);
    const bf16* row3 = row1 - (long)sy * (long)(L+1);
    const bf16* row4 = row1 - (long)(64*sx + sy) * (long)(L+1);
    bool qok[8];
    #pragma unroll
    for (int e = 0; e < 8; e++) qok[e] = (unsigned)(acol + e - sy) < 64u;

    f32x4 acc[2][3] = {};

    for (int kk = 0; kk < 64; kk++){
        int k0 = kk * 64;
        bool c2 = (unsigned)(kk - sx) < 64u;
        bool m2 = r2 && c2, m3 = r3, m4 = r4 && c2;
        int be = k0 + acol;
        __syncthreads();
        uint w1[4], w2[4], w3[5], w4[5];
        *(uint4*)&w1[0] = ((const uu4*)(row1 + be))->v;
        *(uint4*)&w2[0] = ((const uu4*)(row2 + be))->v;
        {
            const uint* p3 = (const uint*)(row3 + be - 1);
            *(uint4*)&w3[0] = ((const uu4*)p3)->v;  w3[4] = p3[4];
            const uint* p4 = (const uint*)(row4 + be - 1);
            *(uint4*)&w4[0] = ((const uu4*)p4)->v;  w4[4] = p4[4];
        }
        short sv[8];
        #pragma unroll
        for (int ii = 0; ii < 4; ii++){
            uint a1 = w1[ii];
            uint a2 = w2[ii];
            uint a3 = (w3[ii] >> 16) | (w3[ii+1] << 16);
            uint a4 = (w4[ii] >> 16) | (w4[ii+1] << 16);
            float f1l = u2f(a1 << 16), f1h = u2f(a1 & 0xffff0000u);
            float f2l = u2f(a2 << 16), f2h = u2f(a2 & 0xffff0000u);
            float f3l = u2f(a3 << 16), f3h = u2f(a3 & 0xffff0000u);
            float f4l = u2f(a4 << 16), f4h = u2f(a4 & 0xffff0000u);
            float sl = f1l + (m2 ? f2l : 0.f)
                     + ((m3 && qok[2*ii  ]) ? f3l : 0.f)
                     + ((m4 && qok[2*ii  ]) ? f4l : 0.f);
            float sh = f1h + (m2 ? f2h : 0.f)
                     + ((m3 && qok[2*ii+1]) ? f3h : 0.f)
                     + ((m4 && qok[2*ii+1]) ? f4h : 0.f);
            sv[2*ii]   = f2bf_s(sl);
            sv[2*ii+1] = f2bf_s(sh);
        }
        *(bf16x8*)&Ab[arow][acol] = *(bf16x8*)&sv[0];
        #pragma unroll
        for (int r = 0; r < 6; r++){
            int e2 = r*256 + t; int c2r = e2 >> 3, kc = e2 & 7;
            *(uint4*)&Bb[c2r][kc*8] = *(const uint4*)(Bm + (size_t)c2r*L + k0 + kc*8);
        }
        __syncthreads();
        #pragma unroll
        for (int kk2 = 0; kk2 < 2; kk2++){
            bf16x8 a[2], bfr[3];
            #pragma unroll
            for (int mt = 0; mt < 2; mt++)
                a[mt] = *(bf16x8*)&Ab[mt*16 + lr][kk2*32 + lq*8];
            #pragma unroll
            for (int nt = 0; nt < 3; nt++)
                bfr[nt] = *(bf16x8*)&Bb[wv*48 + nt*16 + lr][kk2*32 + lq*8];
            #pragma unroll
            for (int mt = 0; mt < 2; mt++)
              #pragma unroll
              for (int nt = 0; nt < 3; nt++)
                acc[mt][nt] = __builtin_amdgcn_mfma_f32_16x16x32_bf16(a[mt], bfr[nt], acc[mt][nt], 0,0,0);
        }
    }
    #pragma unroll
    for (int mt = 0; mt < 2; mt++)
      #pragma unroll
      for (int nt = 0; nt < 3; nt++)
        #pragma unroll
        for (int r = 0; r < 4; r++){
            int mm = m0 + mt*16 + lq*4 + r;
            int Xo = mm >> 6, Yo = mm & 63;
            int x = 2*Xo + dx, y = 2*Yo + dy, c2 = wv*48 + nt*16 + lr;
            out[(size_t)((batch*HF + x)*HF + y)*C + c2] = 0.25f * acc[mt][nt][r];
        }
}

// ---------------- host ----------------
extern "C" void kernel_launch(void* const* d_in, const int* in_sizes, int n_in,
                              void* d_out, int out_size, void* d_ws, size_t ws_size,
                              hipStream_t stream){
    const float* f    = (const float*)d_in[0];
    const float* b    = (const float*)d_in[1];
    const float* mask = (const float*)d_in[2];
    float* out = (float*)d_out;
    char* ws = (char*)d_ws;

    constexpr size_t off_G     = 1179648ull;               // 64 MB, 1.125 MB guards
    constexpr size_t off_F1    = 69468160ull;              // 64 MB
    constexpr size_t off_attn  = 137232384ull;             // 32 MB, 640 KB guards
    constexpr size_t off_bparT = 171442176ull;             // 6.29 MB
    constexpr size_t off_ss    = 177733632ull;
    constexpr size_t off_rn    = 177750016ull;
    constexpr size_t off_mmv   = 177766656ull;

    float* G    = (float*)(ws + off_G);
    float* F1   = (float*)(ws + off_F1);
    bf16*  attn = (bf16*) (ws + off_attn);
    bf16*  bpar = (bf16*) (ws + off_F1);                   // alias: dead before F1 written
    bf16*  fdh  = (bf16*) (ws + off_attn);                 // alias: dead before attn written
    bf16*  fdl  = (bf16*) (ws + off_attn + 1572864ull);
    bf16*  bdh  = (bf16*) (ws + off_attn + 3145728ull);
    bf16*  bdl  = (bf16*) (ws + off_attn + 4718592ull);
    bf16*  bparT= (bf16*) (ws + off_bparT);
    float* ss    = (float*)(ws + off_ss);
    float* rnorm = (float*)(ws + off_rn) + 16;
    float* mmv   = (float*)(ws + off_mmv);

    for (int batch = 0; batch < 2; batch++){
        prep_kernel  <<<dim3(4096),    dim3(192), 0, stream>>>(f, b, fdh, fdl, bdh, bdl, bpar, ss, batch);
        normmm_kernel<<<dim3(16),      dim3(256), 0, stream>>>(mask, ss, rnorm, mmv);
        repack_kernel<<<dim3(3,64,4),  dim3(256), 0, stream>>>(bpar, bparT);
        gemm_g       <<<dim3(32,32),   dim3(256), 0, stream>>>(fdh, fdl, bdh, bdl, G);
        s1f_kernel   <<<dim3(2,4096),  dim3(256), 0, stream>>>(G, rnorm, F1);
        fsoft_kernel <<<dim3(4096),    dim3(256), 0, stream>>>(F1, mmv, attn);
        gemm_paste   <<<dim3(128,4),   dim3(256), 0, stream>>>(attn, bparT, out, batch);
    }
}